// Round 6
// baseline (395.782 us; speedup 1.0000x reference)
//
#include <hip/hip_runtime.h>
#include <hip/hip_bf16.h>

// GAT-style graph attention. N=50000, E=600000, FEAT=128, H=8, D=16.
// R6: fill's 3 scattered streams packed to 2 ({d,pd} int2 @ ps, s @ pd);
//     fill fused with qkv MFMA (write-latency hides under MFMA);
//     hist+converts fused into one prep kernel; nontemporal scatter stores.

#define FEAT 128
#define NHEAD 8
#define NPAD 50048   // N rounded up to multiple of 64

typedef __attribute__((ext_vector_type(8))) short bf16x8;
typedef __attribute__((ext_vector_type(4))) float f32x4;

__device__ __forceinline__ unsigned short f2bf(float f) {
    unsigned u = __float_as_uint(f);
    u += 0x7fffu + ((u >> 16) & 1u);
    return (unsigned short)(u >> 16);
}
__device__ __forceinline__ float bf2f_lo(unsigned u) { return __uint_as_float(u << 16); }
__device__ __forceinline__ float bf2f_hi(unsigned u) { return __uint_as_float(u & 0xffff0000u); }

// ---- fused prep: hist2 | convert_x | convert_w (block-range split) ----
__global__ __launch_bounds__(256) void prep_kernel(
    const int* __restrict__ srcs, const int* __restrict__ dsts,
    int* __restrict__ counts,
    const float* __restrict__ X, unsigned short* __restrict__ Xb, int total8,
    const float* __restrict__ Wq, const float* __restrict__ Wk,
    const float* __restrict__ Wv, const float* __restrict__ Wo,
    unsigned short* __restrict__ Wb,
    int N, int E, int histBlocks, int convxBlocks)
{
    int b = blockIdx.x;
    if (b < histBlocks) {
        int e = b * 256 + threadIdx.x;
        if (e < E) {
            atomicAdd(counts + srcs[e], 1);
            atomicAdd(counts + N + dsts[e], 1);
        }
        return;
    }
    b -= histBlocks;
    if (b < convxBlocks) {
        int i = b * 256 + threadIdx.x;
        if (i >= total8) return;
        const float4* xp = (const float4*)X + (size_t)i * 2;
        float4 x0 = xp[0], x1 = xp[1];
        uint4 o;
        o.x = (unsigned)f2bf(x0.x) | ((unsigned)f2bf(x0.y) << 16);
        o.y = (unsigned)f2bf(x0.z) | ((unsigned)f2bf(x0.w) << 16);
        o.z = (unsigned)f2bf(x1.x) | ((unsigned)f2bf(x1.y) << 16);
        o.w = (unsigned)f2bf(x1.z) | ((unsigned)f2bf(x1.w) << 16);
        ((uint4*)Xb)[i] = o;
        return;
    }
    b -= convxBlocks;
    int i = b * 256 + threadIdx.x;
    if (i >= 4 * 2048) return;
    int mat = i >> 11, idx = i & 2047;
    const float* W = (mat == 0) ? Wq : (mat == 1) ? Wk : (mat == 2) ? Wv : Wo;
    const float4* xp = (const float4*)W + (size_t)idx * 2;
    float4 x0 = xp[0], x1 = xp[1];
    uint4 o;
    o.x = (unsigned)f2bf(x0.x) | ((unsigned)f2bf(x0.y) << 16);
    o.y = (unsigned)f2bf(x0.z) | ((unsigned)f2bf(x0.w) << 16);
    o.z = (unsigned)f2bf(x1.x) | ((unsigned)f2bf(x1.y) << 16);
    o.w = (unsigned)f2bf(x1.z) | ((unsigned)f2bf(x1.w) << 16);
    ((uint4*)(Wb + (size_t)mat * 16384))[idx] = o;
}

// ---- scan over concatenated [src counts | dest counts] (2N elems) ----
__global__ __launch_bounds__(256) void scan1_kernel(
    const int* __restrict__ counts, int* __restrict__ offsets,
    int* __restrict__ blocksums, int NT)
{
    __shared__ int buf[256];
    int t = threadIdx.x, i = blockIdx.x * 256 + t;
    int v = (i < NT) ? counts[i] : 0;
    buf[t] = v; __syncthreads();
    int x = v;
    #pragma unroll
    for (int off = 1; off < 256; off <<= 1) {
        int y = (t >= off) ? buf[t - off] : 0;
        __syncthreads();
        x += y; buf[t] = x;
        __syncthreads();
    }
    if (i < NT) offsets[i] = x - v;
    if (t == 255) blocksums[blockIdx.x] = x;
}

__global__ __launch_bounds__(512) void scan2_kernel(
    int* __restrict__ blocksums, int* __restrict__ blockoffs, int NB)
{
    __shared__ int buf[512];
    int t = threadIdx.x;
    int v = (t < NB) ? blocksums[t] : 0;
    buf[t] = v; __syncthreads();
    int x = v;
    #pragma unroll
    for (int off = 1; off < 512; off <<= 1) {
        int y = (t >= off) ? buf[t - off] : 0;
        __syncthreads();
        x += y; buf[t] = x;
        __syncthreads();
    }
    if (t < NB) blockoffs[t] = x - v;
}

__global__ __launch_bounds__(256) void scan3_kernel(
    int* __restrict__ offsets, const int* __restrict__ blockoffs,
    int* __restrict__ cursor, int NT)
{
    int i = blockIdx.x * 256 + threadIdx.x;
    if (i < NT) {
        int o = offsets[i] + blockoffs[blockIdx.x];
        offsets[i] = o;
        cursor[i] = o;
    }
}

// ---- fused: fill both CSRs (packed) | qkv MFMA (block-range split) ----
// fill: sd_rec[ps] = {d, pd} (8B nt store), src_sorted[pd] = s (4B nt store)
// qkv:  wave owns 32-col strip, B frags persistent in regs, grid-stride tiles
__global__ __launch_bounds__(256) void fill_qkv_kernel(
    const int* __restrict__ srcs, const int* __restrict__ dsts,
    int* __restrict__ cursor, int2* __restrict__ sd_rec,
    int* __restrict__ src_sorted,
    const unsigned short* __restrict__ Xb, const unsigned short* __restrict__ Wb,
    const float* __restrict__ bq, const float* __restrict__ bk, const float* __restrict__ bv,
    unsigned short* __restrict__ Q, unsigned short* __restrict__ K,
    unsigned short* __restrict__ V,
    int N, int E, int fillBlocks, int qkvBlocks, int numTiles)
{
    if ((int)blockIdx.x < fillBlocks) {
        int e = blockIdx.x * 256 + threadIdx.x;
        if (e < E) {
            int s = srcs[e], d = dsts[e];
            int ps = atomicAdd(cursor + s, 1);
            int pd = atomicAdd(cursor + N + d, 1) - E;
            unsigned long long rec = ((unsigned long long)(unsigned)pd << 32) | (unsigned)d;
            __builtin_nontemporal_store(rec, (unsigned long long*)sd_rec + ps);
            __builtin_nontemporal_store(s, src_sorted + pd);
        }
        return;
    }

    const int lane = threadIdx.x & 63;
    const int wave = threadIdx.x >> 6;
    const int m = lane & 15, quad = lane >> 4;
    const int colbase = wave * 32;

    bf16x8 bfr[3][2][4];
    #pragma unroll
    for (int mat = 0; mat < 3; mat++)
        #pragma unroll
        for (int ctl = 0; ctl < 2; ctl++) {
            const unsigned short* wrow =
                Wb + mat * 16384 + (size_t)(colbase + ctl * 16 + m) * FEAT + quad * 8;
            #pragma unroll
            for (int kc = 0; kc < 4; kc++)
                bfr[mat][ctl][kc] = *(const bf16x8*)(wrow + kc * 32);
        }

    const float* bias_p[3] = {bq, bk, bv};
    float bias[3][2];
    #pragma unroll
    for (int mat = 0; mat < 3; mat++)
        #pragma unroll
        for (int ctl = 0; ctl < 2; ctl++)
            bias[mat][ctl] = bias_p[mat][colbase + ctl * 16 + m];

    unsigned short* outp[3] = {Q, K, V};
    const int qb = blockIdx.x - fillBlocks;

    for (int tile = qb; tile < numTiles; tile += qkvBlocks) {
        const int row0 = tile * 16;
        const unsigned short* arow = Xb + (size_t)(row0 + m) * FEAT + quad * 8;
        bf16x8 a[4];
        #pragma unroll
        for (int kc = 0; kc < 4; kc++) a[kc] = *(const bf16x8*)(arow + kc * 32);
        f32x4 acc[3][2];
        #pragma unroll
        for (int mat = 0; mat < 3; mat++)
            #pragma unroll
            for (int ctl = 0; ctl < 2; ctl++) acc[mat][ctl] = (f32x4){0.f, 0.f, 0.f, 0.f};
        #pragma unroll
        for (int kc = 0; kc < 4; kc++)
            #pragma unroll
            for (int mat = 0; mat < 3; mat++)
                #pragma unroll
                for (int ctl = 0; ctl < 2; ctl++)
                    acc[mat][ctl] = __builtin_amdgcn_mfma_f32_16x16x32_bf16(
                        a[kc], bfr[mat][ctl][kc], acc[mat][ctl], 0, 0, 0);
        #pragma unroll
        for (int mat = 0; mat < 3; mat++)
            #pragma unroll
            for (int ctl = 0; ctl < 2; ctl++)
                #pragma unroll
                for (int reg = 0; reg < 4; reg++) {
                    int row = row0 + quad * 4 + reg;
                    if (row < N)
                        outp[mat][(size_t)row * FEAT + colbase + ctl * 16 + m] =
                            f2bf(acc[mat][ctl][reg] + bias[mat][ctl]);
                }
    }
}

// ---- scores: one wave per SRC node; Q row in regs; per-edge random K-row
//      load; shfl-reduce; writes RAW exp(w) scattered into dest-CSR order;
//      rsegsum = 1/sum in src order ----
__global__ __launch_bounds__(256) void scores_kernel(
    const int* __restrict__ offsets, const int* __restrict__ counts,
    const int2* __restrict__ sd_rec,
    const unsigned short* __restrict__ Q, const unsigned short* __restrict__ K,
    float* __restrict__ wraw, float* __restrict__ rsegsum, int N)
{
    int node = blockIdx.x * 4 + (threadIdx.x >> 6);
    if (node >= N) return;
    int lane = threadIdx.x & 63;
    int start = offsets[node], deg = counts[node];
    unsigned q2 = *(const unsigned*)(Q + (size_t)node * FEAT + lane * 2);
    float qlo = bf2f_lo(q2), qhi = bf2f_hi(q2);
    float acc = 0.f;
    const int srcl = (lane & 7) * 8;

    int j = 0;
    for (; j + 2 <= deg; j += 2) {
        int pos = start + j;
        int2 r0 = sd_rec[pos], r1 = sd_rec[pos + 1];
        unsigned k0 = *(const unsigned*)(K + (size_t)r0.x * FEAT + lane * 2);
        unsigned k1 = *(const unsigned*)(K + (size_t)r1.x * FEAT + lane * 2);
        float p0 = qlo * bf2f_lo(k0) + qhi * bf2f_hi(k0);
        float p1 = qlo * bf2f_lo(k1) + qhi * bf2f_hi(k1);
        p0 += __shfl_xor(p0, 1); p1 += __shfl_xor(p1, 1);
        p0 += __shfl_xor(p0, 2); p1 += __shfl_xor(p1, 2);
        p0 += __shfl_xor(p0, 4); p1 += __shfl_xor(p1, 4);
        float w0 = __expf(p0 * 0.25f);
        float w1 = __expf(p1 * 0.25f);
        acc += w0 + w1;
        float wo0 = __shfl(w0, srcl);
        float wo1 = __shfl(w1, srcl);
        if (lane < 8) {
            wraw[(size_t)r0.y * NHEAD + lane] = wo0;
            wraw[(size_t)r1.y * NHEAD + lane] = wo1;
        }
    }
    for (; j < deg; j++) {
        int pos = start + j;
        int2 r = sd_rec[pos];
        unsigned k2 = *(const unsigned*)(K + (size_t)r.x * FEAT + lane * 2);
        float p = qlo * bf2f_lo(k2) + qhi * bf2f_hi(k2);
        p += __shfl_xor(p, 1);
        p += __shfl_xor(p, 2);
        p += __shfl_xor(p, 4);
        float wv = __expf(p * 0.25f);
        acc += wv;
        float wo = __shfl(wv, srcl);
        if (lane < 8) wraw[(size_t)r.y * NHEAD + lane] = wo;
    }
    float at = __shfl(acc, srcl);
    if (lane < 8) rsegsum[(size_t)node * NHEAD + lane] = 1.0f / at;
}

// ---- gather: one wave per dest node; streaming src_sorted/wraw,
//      rsegsum[src] normalization, 4x-unrolled random V-row loads ----
__global__ __launch_bounds__(256) void gather_kernel(
    const int* __restrict__ offsets, const int* __restrict__ counts,
    const int* __restrict__ src_sorted, const float* __restrict__ wraw,
    const float* __restrict__ rsegsum, const unsigned short* __restrict__ V,
    unsigned short* __restrict__ agg, int N, int E)
{
    int node = blockIdx.x * 4 + (threadIdx.x >> 6);
    if (node >= N) return;
    int lane = threadIdx.x & 63;
    int h = lane >> 3;
    int start = offsets[node] - E, deg = counts[node];
    float ax = 0.f, ay = 0.f;
    int j = 0;
    for (; j + 4 <= deg; j += 4) {
        int p = start + j;
        int s0 = src_sorted[p], s1 = src_sorted[p + 1];
        int s2 = src_sorted[p + 2], s3 = src_sorted[p + 3];
        float w0 = wraw[(size_t)(p + 0) * NHEAD + h] * rsegsum[(size_t)s0 * NHEAD + h];
        float w1 = wraw[(size_t)(p + 1) * NHEAD + h] * rsegsum[(size_t)s1 * NHEAD + h];
        float w2 = wraw[(size_t)(p + 2) * NHEAD + h] * rsegsum[(size_t)s2 * NHEAD + h];
        float w3 = wraw[(size_t)(p + 3) * NHEAD + h] * rsegsum[(size_t)s3 * NHEAD + h];
        unsigned v0 = *(const unsigned*)(V + (size_t)s0 * FEAT + lane * 2);
        unsigned v1 = *(const unsigned*)(V + (size_t)s1 * FEAT + lane * 2);
        unsigned v2 = *(const unsigned*)(V + (size_t)s2 * FEAT + lane * 2);
        unsigned v3 = *(const unsigned*)(V + (size_t)s3 * FEAT + lane * 2);
        ax += w0 * bf2f_lo(v0) + w1 * bf2f_lo(v1) + w2 * bf2f_lo(v2) + w3 * bf2f_lo(v3);
        ay += w0 * bf2f_hi(v0) + w1 * bf2f_hi(v1) + w2 * bf2f_hi(v2) + w3 * bf2f_hi(v3);
    }
    for (; j < deg; j++) {
        int p = start + j;
        int s = src_sorted[p];
        float w = wraw[(size_t)p * NHEAD + h] * rsegsum[(size_t)s * NHEAD + h];
        unsigned v = *(const unsigned*)(V + (size_t)s * FEAT + lane * 2);
        ax += w * bf2f_lo(v);
        ay += w * bf2f_hi(v);
    }
    unsigned o = (unsigned)f2bf(ax) | ((unsigned)f2bf(ay) << 16);
    *(unsigned*)(agg + (size_t)node * FEAT + lane * 2) = o;
}

// ---- out MFMA GEMM: persistent-B structure, 1 matrix, f32 out ----
__global__ __launch_bounds__(256) void out_mfma_kernel(
    const unsigned short* __restrict__ Ab, const unsigned short* __restrict__ Wob,
    const float* __restrict__ bo, float* __restrict__ out, int N, int numTiles)
{
    const int lane = threadIdx.x & 63;
    const int wave = threadIdx.x >> 6;
    const int m = lane & 15, quad = lane >> 4;
    const int colbase = wave * 32;

    bf16x8 bfr[2][4];
    #pragma unroll
    for (int ctl = 0; ctl < 2; ctl++) {
        const unsigned short* wrow = Wob + (size_t)(colbase + ctl * 16 + m) * FEAT + quad * 8;
        #pragma unroll
        for (int kc = 0; kc < 4; kc++)
            bfr[ctl][kc] = *(const bf16x8*)(wrow + kc * 32);
    }
    float bias[2];
    #pragma unroll
    for (int ctl = 0; ctl < 2; ctl++) bias[ctl] = bo[colbase + ctl * 16 + m];

    for (int tile = blockIdx.x; tile < numTiles; tile += gridDim.x) {
        const int row0 = tile * 16;
        const unsigned short* arow = Ab + (size_t)(row0 + m) * FEAT + quad * 8;
        bf16x8 a[4];
        #pragma unroll
        for (int kc = 0; kc < 4; kc++) a[kc] = *(const bf16x8*)(arow + kc * 32);
        f32x4 acc[2];
        #pragma unroll
        for (int ctl = 0; ctl < 2; ctl++) acc[ctl] = (f32x4){0.f, 0.f, 0.f, 0.f};
        #pragma unroll
        for (int kc = 0; kc < 4; kc++)
            #pragma unroll
            for (int ctl = 0; ctl < 2; ctl++)
                acc[ctl] = __builtin_amdgcn_mfma_f32_16x16x32_bf16(
                    a[kc], bfr[ctl][kc], acc[ctl], 0, 0, 0);
        #pragma unroll
        for (int ctl = 0; ctl < 2; ctl++)
            #pragma unroll
            for (int reg = 0; reg < 4; reg++) {
                int row = row0 + quad * 4 + reg;
                if (row < N)
                    out[(size_t)row * FEAT + colbase + ctl * 16 + m] = acc[ctl][reg] + bias[ctl];
            }
    }
}

extern "C" void kernel_launch(void* const* d_in, const int* in_sizes, int n_in,
                              void* d_out, int out_size, void* d_ws, size_t ws_size,
                              hipStream_t stream) {
    const float* X  = (const float*)d_in[0];
    const int*   ei = (const int*)d_in[1];
    const float* Wq = (const float*)d_in[2];
    const float* bq = (const float*)d_in[3];
    const float* Wk = (const float*)d_in[4];
    const float* bk = (const float*)d_in[5];
    const float* Wv = (const float*)d_in[6];
    const float* bv = (const float*)d_in[7];
    const float* Wo = (const float*)d_in[8];
    const float* bo = (const float*)d_in[9];
    float* out = (float*)d_out;

    const int N = in_sizes[0] / FEAT;        // 50000
    const int E = in_sizes[1] / 2;           // 600000
    const int* srcs = ei;
    const int* dsts = ei + E;
    const size_t NF2 = (size_t)NPAD * FEAT * 2;

    char* w = (char*)d_ws;
    unsigned short* Xb = (unsigned short*)w;  w += NF2;       // also Ab (after qkv)
    unsigned short* Qb = (unsigned short*)w;  w += NF2;
    unsigned short* Kb = (unsigned short*)w;  w += NF2;
    unsigned short* Vb = (unsigned short*)w;  w += NF2;
    unsigned short* Wb = (unsigned short*)w;  w += (size_t)4 * 16384 * 2;
    float* wraw        = (float*)w;           w += (size_t)E * NHEAD * 4;
    float* rsegsum     = (float*)w;           w += (size_t)N * NHEAD * 4;
    int* counts        = (int*)w;             w += (size_t)2 * N * 4;
    int* offsets       = (int*)w;             w += (size_t)2 * N * 4;
    int* cursor        = (int*)w;             w += (size_t)2 * N * 4;
    int* blocksums     = (int*)w;             w += 512 * 4;
    int* blockoffs     = (int*)w;             w += 512 * 4;
    int2* sd_rec       = (int2*)w;            w += (size_t)E * 8;
    int* src_sorted    = (int*)w;             w += (size_t)E * 4;

    unsigned short* Ab = Xb;   // Xb dead after qkv

    hipMemsetAsync(counts, 0, (size_t)2 * N * sizeof(int), stream);

    int e_blocks = (E + 255) / 256;          // 2344
    int x8 = N * FEAT / 8;
    int convx_blocks = (x8 + 255) / 256;     // 3125
    int convw_blocks = 32;
    prep_kernel<<<e_blocks + convx_blocks + convw_blocks, 256, 0, stream>>>(
        srcs, dsts, counts, X, Xb, x8, Wq, Wk, Wv, Wo, Wb,
        N, E, e_blocks, convx_blocks);

    int NT = 2 * N;
    int NB2 = (NT + 255) / 256;
    scan1_kernel<<<NB2, 256, 0, stream>>>(counts, offsets, blocksums, NT);
    scan2_kernel<<<1, 512, 0, stream>>>(blocksums, blockoffs, NB2);
    scan3_kernel<<<NB2, 256, 0, stream>>>(offsets, blockoffs, cursor, NT);

    int numTiles = NPAD / 16;   // 3128
    int qkv_blocks = 782;
    fill_qkv_kernel<<<e_blocks + qkv_blocks, 256, 0, stream>>>(
        srcs, dsts, cursor, sd_rec, src_sorted,
        Xb, Wb, bq, bk, bv, Qb, Kb, Vb,
        N, E, e_blocks, qkv_blocks, numTiles);

    int node_blocks = (N + 3) / 4;
    scores_kernel<<<node_blocks, 256, 0, stream>>>(
        offsets, counts, sd_rec, Qb, Kb, wraw, rsegsum, N);

    gather_kernel<<<node_blocks, 256, 0, stream>>>(
        offsets + N, counts + N, src_sorted, wraw, rsegsum, Vb, Ab, N, E);

    out_mfma_kernel<<<782, 256, 0, stream>>>(Ab, Wb + 3 * 16384, bo, out, N, numTiles);
}

// Round 7
// 304.761 us; speedup vs baseline: 1.2987x; 1.2987x over previous
//
#include <hip/hip_runtime.h>
#include <hip/hip_bf16.h>

// GAT-style graph attention. N=50000, E=600000, FEAT=128, H=8, D=16.
// R7: single dest-CSR only. fill scatters ONE 4B stream (rec[pd]=src).
//     sumexp pass runs wave-per-dest (K in regs, random Q rows, atomicAdd
//     into L2-resident segsum[src], sequential wraw writes). gather
//     normalizes via rsegsum[src]. De-fused qkv (R6 fusion regressed:
//     84 VGPR starved the latency-bound fill of occupancy).

#define FEAT 128
#define NHEAD 8
#define NPAD 50048   // N rounded up to multiple of 64

typedef __attribute__((ext_vector_type(8))) short bf16x8;
typedef __attribute__((ext_vector_type(4))) float f32x4;

__device__ __forceinline__ unsigned short f2bf(float f) {
    unsigned u = __float_as_uint(f);
    u += 0x7fffu + ((u >> 16) & 1u);
    return (unsigned short)(u >> 16);
}
__device__ __forceinline__ float bf2f_lo(unsigned u) { return __uint_as_float(u << 16); }
__device__ __forceinline__ float bf2f_hi(unsigned u) { return __uint_as_float(u & 0xffff0000u); }

// ---- fused prep: dest histogram | convert_x | convert_w ----
__global__ __launch_bounds__(256) void prep_kernel(
    const int* __restrict__ dsts, int* __restrict__ counts,
    const float* __restrict__ X, unsigned short* __restrict__ Xb, int total8,
    const float* __restrict__ Wq, const float* __restrict__ Wk,
    const float* __restrict__ Wv, const float* __restrict__ Wo,
    unsigned short* __restrict__ Wb,
    int E, int histBlocks, int convxBlocks)
{
    int b = blockIdx.x;
    if (b < histBlocks) {
        int e = b * 256 + threadIdx.x;
        if (e < E) atomicAdd(counts + dsts[e], 1);
        return;
    }
    b -= histBlocks;
    if (b < convxBlocks) {
        int i = b * 256 + threadIdx.x;
        if (i >= total8) return;
        const float4* xp = (const float4*)X + (size_t)i * 2;
        float4 x0 = xp[0], x1 = xp[1];
        uint4 o;
        o.x = (unsigned)f2bf(x0.x) | ((unsigned)f2bf(x0.y) << 16);
        o.y = (unsigned)f2bf(x0.z) | ((unsigned)f2bf(x0.w) << 16);
        o.z = (unsigned)f2bf(x1.x) | ((unsigned)f2bf(x1.y) << 16);
        o.w = (unsigned)f2bf(x1.z) | ((unsigned)f2bf(x1.w) << 16);
        ((uint4*)Xb)[i] = o;
        return;
    }
    b -= convxBlocks;
    int i = b * 256 + threadIdx.x;
    if (i >= 4 * 2048) return;
    int mat = i >> 11, idx = i & 2047;
    const float* W = (mat == 0) ? Wq : (mat == 1) ? Wk : (mat == 2) ? Wv : Wo;
    const float4* xp = (const float4*)W + (size_t)idx * 2;
    float4 x0 = xp[0], x1 = xp[1];
    uint4 o;
    o.x = (unsigned)f2bf(x0.x) | ((unsigned)f2bf(x0.y) << 16);
    o.y = (unsigned)f2bf(x0.z) | ((unsigned)f2bf(x0.w) << 16);
    o.z = (unsigned)f2bf(x1.x) | ((unsigned)f2bf(x1.y) << 16);
    o.w = (unsigned)f2bf(x1.z) | ((unsigned)f2bf(x1.w) << 16);
    ((uint4*)(Wb + (size_t)mat * 16384))[idx] = o;
}

// ---- exclusive scan over N dest-counts ----
__global__ __launch_bounds__(256) void scan1_kernel(
    const int* __restrict__ counts, int* __restrict__ offsets,
    int* __restrict__ blocksums, int NT)
{
    __shared__ int buf[256];
    int t = threadIdx.x, i = blockIdx.x * 256 + t;
    int v = (i < NT) ? counts[i] : 0;
    buf[t] = v; __syncthreads();
    int x = v;
    #pragma unroll
    for (int off = 1; off < 256; off <<= 1) {
        int y = (t >= off) ? buf[t - off] : 0;
        __syncthreads();
        x += y; buf[t] = x;
        __syncthreads();
    }
    if (i < NT) offsets[i] = x - v;
    if (t == 255) blocksums[blockIdx.x] = x;
}

__global__ __launch_bounds__(256) void scan2_kernel(
    int* __restrict__ blocksums, int* __restrict__ blockoffs, int NB)
{
    __shared__ int buf[256];
    int t = threadIdx.x;
    int v = (t < NB) ? blocksums[t] : 0;
    buf[t] = v; __syncthreads();
    int x = v;
    #pragma unroll
    for (int off = 1; off < 256; off <<= 1) {
        int y = (t >= off) ? buf[t - off] : 0;
        __syncthreads();
        x += y; buf[t] = x;
        __syncthreads();
    }
    if (t < NB) blockoffs[t] = x - v;
}

__global__ __launch_bounds__(256) void scan3_kernel(
    int* __restrict__ offsets, const int* __restrict__ blockoffs,
    int* __restrict__ cursor, int NT)
{
    int i = blockIdx.x * 256 + threadIdx.x;
    if (i < NT) {
        int o = offsets[i] + blockoffs[blockIdx.x];
        offsets[i] = o;
        cursor[i] = o;
    }
}

// ---- fill dest-CSR: ONE scattered 4B stream ----
__global__ __launch_bounds__(256) void fill_kernel(
    const int* __restrict__ srcs, const int* __restrict__ dsts,
    int* __restrict__ cursor, int* __restrict__ rec, int E)
{
    int e = blockIdx.x * 256 + threadIdx.x;
    if (e < E) {
        int s = srcs[e], d = dsts[e];
        int pd = atomicAdd(cursor + d, 1);
        __builtin_nontemporal_store(s, rec + pd);
    }
}

// ---- QKV MFMA GEMM: wave owns 32-col strip, B frags persistent in regs ----
__global__ __launch_bounds__(256) void qkv_mfma_kernel(
    const unsigned short* __restrict__ Xb, const unsigned short* __restrict__ Wb,
    const float* __restrict__ bq, const float* __restrict__ bk, const float* __restrict__ bv,
    unsigned short* __restrict__ Q, unsigned short* __restrict__ K,
    unsigned short* __restrict__ V, int N, int numTiles)
{
    const int lane = threadIdx.x & 63;
    const int wave = threadIdx.x >> 6;
    const int m = lane & 15, quad = lane >> 4;
    const int colbase = wave * 32;

    bf16x8 bfr[3][2][4];
    #pragma unroll
    for (int mat = 0; mat < 3; mat++)
        #pragma unroll
        for (int ctl = 0; ctl < 2; ctl++) {
            const unsigned short* wrow =
                Wb + mat * 16384 + (size_t)(colbase + ctl * 16 + m) * FEAT + quad * 8;
            #pragma unroll
            for (int kc = 0; kc < 4; kc++)
                bfr[mat][ctl][kc] = *(const bf16x8*)(wrow + kc * 32);
        }

    const float* bias_p[3] = {bq, bk, bv};
    float bias[3][2];
    #pragma unroll
    for (int mat = 0; mat < 3; mat++)
        #pragma unroll
        for (int ctl = 0; ctl < 2; ctl++)
            bias[mat][ctl] = bias_p[mat][colbase + ctl * 16 + m];

    unsigned short* outp[3] = {Q, K, V};

    for (int tile = blockIdx.x; tile < numTiles; tile += gridDim.x) {
        const int row0 = tile * 16;
        const unsigned short* arow = Xb + (size_t)(row0 + m) * FEAT + quad * 8;
        bf16x8 a[4];
        #pragma unroll
        for (int kc = 0; kc < 4; kc++) a[kc] = *(const bf16x8*)(arow + kc * 32);
        f32x4 acc[3][2];
        #pragma unroll
        for (int mat = 0; mat < 3; mat++)
            #pragma unroll
            for (int ctl = 0; ctl < 2; ctl++) acc[mat][ctl] = (f32x4){0.f, 0.f, 0.f, 0.f};
        #pragma unroll
        for (int kc = 0; kc < 4; kc++)
            #pragma unroll
            for (int mat = 0; mat < 3; mat++)
                #pragma unroll
                for (int ctl = 0; ctl < 2; ctl++)
                    acc[mat][ctl] = __builtin_amdgcn_mfma_f32_16x16x32_bf16(
                        a[kc], bfr[mat][ctl][kc], acc[mat][ctl], 0, 0, 0);
        #pragma unroll
        for (int mat = 0; mat < 3; mat++)
            #pragma unroll
            for (int ctl = 0; ctl < 2; ctl++)
                #pragma unroll
                for (int reg = 0; reg < 4; reg++) {
                    int row = row0 + quad * 4 + reg;
                    if (row < N)
                        outp[mat][(size_t)row * FEAT + colbase + ctl * 16 + m] =
                            f2bf(acc[mat][ctl][reg] + bias[mat][ctl]);
                }
    }
}

// ---- sumexp: one wave per DEST node. K row in regs; per edge one random
//      Q-row load; shfl-reduce per head; w -> wraw (sequential) and
//      atomicAdd segsum[src] (1.6MB, L2-resident) ----
__global__ __launch_bounds__(256) void sumexp_kernel(
    const int* __restrict__ offsets, const int* __restrict__ counts,
    const int* __restrict__ rec,
    const unsigned short* __restrict__ Q, const unsigned short* __restrict__ K,
    float* __restrict__ wraw, float* __restrict__ segsum, int N)
{
    int node = blockIdx.x * 4 + (threadIdx.x >> 6);
    if (node >= N) return;
    int lane = threadIdx.x & 63;
    int start = offsets[node], deg = counts[node];
    unsigned k2 = *(const unsigned*)(K + (size_t)node * FEAT + lane * 2);
    float klo = bf2f_lo(k2), khi = bf2f_hi(k2);
    const int h = lane >> 3;
    const bool wlane = (lane & 7) == 0;

    int j = 0;
    for (; j + 2 <= deg; j += 2) {
        int pos = start + j;
        int s0 = rec[pos], s1 = rec[pos + 1];
        unsigned q0 = *(const unsigned*)(Q + (size_t)s0 * FEAT + lane * 2);
        unsigned q1 = *(const unsigned*)(Q + (size_t)s1 * FEAT + lane * 2);
        float p0 = klo * bf2f_lo(q0) + khi * bf2f_hi(q0);
        float p1 = klo * bf2f_lo(q1) + khi * bf2f_hi(q1);
        p0 += __shfl_xor(p0, 1); p1 += __shfl_xor(p1, 1);
        p0 += __shfl_xor(p0, 2); p1 += __shfl_xor(p1, 2);
        p0 += __shfl_xor(p0, 4); p1 += __shfl_xor(p1, 4);
        float w0 = __expf(p0 * 0.25f);
        float w1 = __expf(p1 * 0.25f);
        if (wlane) {
            wraw[(size_t)pos * NHEAD + h] = w0;
            wraw[(size_t)(pos + 1) * NHEAD + h] = w1;
            atomicAdd(segsum + (size_t)s0 * NHEAD + h, w0);
            atomicAdd(segsum + (size_t)s1 * NHEAD + h, w1);
        }
    }
    for (; j < deg; j++) {
        int pos = start + j;
        int s = rec[pos];
        unsigned q2 = *(const unsigned*)(Q + (size_t)s * FEAT + lane * 2);
        float p = klo * bf2f_lo(q2) + khi * bf2f_hi(q2);
        p += __shfl_xor(p, 1);
        p += __shfl_xor(p, 2);
        p += __shfl_xor(p, 4);
        float w = __expf(p * 0.25f);
        if (wlane) {
            wraw[(size_t)pos * NHEAD + h] = w;
            atomicAdd(segsum + (size_t)s * NHEAD + h, w);
        }
    }
}

// ---- reciprocal of segsum ----
__global__ __launch_bounds__(256) void recip_kernel(float* __restrict__ segsum, int n)
{
    int i = blockIdx.x * 256 + threadIdx.x;
    if (i < n) segsum[i] = 1.0f / segsum[i];
}

// ---- gather: one wave per dest node; streaming rec/wraw, rsegsum[src]
//      normalization, 4x-unrolled random V-row loads ----
__global__ __launch_bounds__(256) void gather_kernel(
    const int* __restrict__ offsets, const int* __restrict__ counts,
    const int* __restrict__ rec, const float* __restrict__ wraw,
    const float* __restrict__ rsegsum, const unsigned short* __restrict__ V,
    unsigned short* __restrict__ agg, int N)
{
    int node = blockIdx.x * 4 + (threadIdx.x >> 6);
    if (node >= N) return;
    int lane = threadIdx.x & 63;
    int h = lane >> 3;
    int start = offsets[node], deg = counts[node];
    float ax = 0.f, ay = 0.f;
    int j = 0;
    for (; j + 4 <= deg; j += 4) {
        int p = start + j;
        int s0 = rec[p], s1 = rec[p + 1];
        int s2 = rec[p + 2], s3 = rec[p + 3];
        float w0 = wraw[(size_t)(p + 0) * NHEAD + h] * rsegsum[(size_t)s0 * NHEAD + h];
        float w1 = wraw[(size_t)(p + 1) * NHEAD + h] * rsegsum[(size_t)s1 * NHEAD + h];
        float w2 = wraw[(size_t)(p + 2) * NHEAD + h] * rsegsum[(size_t)s2 * NHEAD + h];
        float w3 = wraw[(size_t)(p + 3) * NHEAD + h] * rsegsum[(size_t)s3 * NHEAD + h];
        unsigned v0 = *(const unsigned*)(V + (size_t)s0 * FEAT + lane * 2);
        unsigned v1 = *(const unsigned*)(V + (size_t)s1 * FEAT + lane * 2);
        unsigned v2 = *(const unsigned*)(V + (size_t)s2 * FEAT + lane * 2);
        unsigned v3 = *(const unsigned*)(V + (size_t)s3 * FEAT + lane * 2);
        ax += w0 * bf2f_lo(v0) + w1 * bf2f_lo(v1) + w2 * bf2f_lo(v2) + w3 * bf2f_lo(v3);
        ay += w0 * bf2f_hi(v0) + w1 * bf2f_hi(v1) + w2 * bf2f_hi(v2) + w3 * bf2f_hi(v3);
    }
    for (; j < deg; j++) {
        int p = start + j;
        int s = rec[p];
        float w = wraw[(size_t)p * NHEAD + h] * rsegsum[(size_t)s * NHEAD + h];
        unsigned v = *(const unsigned*)(V + (size_t)s * FEAT + lane * 2);
        ax += w * bf2f_lo(v);
        ay += w * bf2f_hi(v);
    }
    unsigned o = (unsigned)f2bf(ax) | ((unsigned)f2bf(ay) << 16);
    *(unsigned*)(agg + (size_t)node * FEAT + lane * 2) = o;
}

// ---- out MFMA GEMM: persistent-B structure, 1 matrix, f32 out ----
__global__ __launch_bounds__(256) void out_mfma_kernel(
    const unsigned short* __restrict__ Ab, const unsigned short* __restrict__ Wob,
    const float* __restrict__ bo, float* __restrict__ out, int N, int numTiles)
{
    const int lane = threadIdx.x & 63;
    const int wave = threadIdx.x >> 6;
    const int m = lane & 15, quad = lane >> 4;
    const int colbase = wave * 32;

    bf16x8 bfr[2][4];
    #pragma unroll
    for (int ctl = 0; ctl < 2; ctl++) {
        const unsigned short* wrow = Wob + (size_t)(colbase + ctl * 16 + m) * FEAT + quad * 8;
        #pragma unroll
        for (int kc = 0; kc < 4; kc++)
            bfr[ctl][kc] = *(const bf16x8*)(wrow + kc * 32);
    }
    float bias[2];
    #pragma unroll
    for (int ctl = 0; ctl < 2; ctl++) bias[ctl] = bo[colbase + ctl * 16 + m];

    for (int tile = blockIdx.x; tile < numTiles; tile += gridDim.x) {
        const int row0 = tile * 16;
        const unsigned short* arow = Ab + (size_t)(row0 + m) * FEAT + quad * 8;
        bf16x8 a[4];
        #pragma unroll
        for (int kc = 0; kc < 4; kc++) a[kc] = *(const bf16x8*)(arow + kc * 32);
        f32x4 acc[2];
        #pragma unroll
        for (int ctl = 0; ctl < 2; ctl++) acc[ctl] = (f32x4){0.f, 0.f, 0.f, 0.f};
        #pragma unroll
        for (int kc = 0; kc < 4; kc++)
            #pragma unroll
            for (int ctl = 0; ctl < 2; ctl++)
                acc[ctl] = __builtin_amdgcn_mfma_f32_16x16x32_bf16(
                    a[kc], bfr[ctl][kc], acc[ctl], 0, 0, 0);
        #pragma unroll
        for (int ctl = 0; ctl < 2; ctl++)
            #pragma unroll
            for (int reg = 0; reg < 4; reg++) {
                int row = row0 + quad * 4 + reg;
                if (row < N)
                    out[(size_t)row * FEAT + colbase + ctl * 16 + m] = acc[ctl][reg] + bias[ctl];
            }
    }
}

extern "C" void kernel_launch(void* const* d_in, const int* in_sizes, int n_in,
                              void* d_out, int out_size, void* d_ws, size_t ws_size,
                              hipStream_t stream) {
    const float* X  = (const float*)d_in[0];
    const int*   ei = (const int*)d_in[1];
    const float* Wq = (const float*)d_in[2];
    const float* bq = (const float*)d_in[3];
    const float* Wk = (const float*)d_in[4];
    const float* bk = (const float*)d_in[5];
    const float* Wv = (const float*)d_in[6];
    const float* bv = (const float*)d_in[7];
    const float* Wo = (const float*)d_in[8];
    const float* bo = (const float*)d_in[9];
    float* out = (float*)d_out;

    const int N = in_sizes[0] / FEAT;        // 50000
    const int E = in_sizes[1] / 2;           // 600000
    const int* srcs = ei;
    const int* dsts = ei + E;
    const size_t NF2 = (size_t)NPAD * FEAT * 2;

    char* w = (char*)d_ws;
    unsigned short* Xb = (unsigned short*)w;  w += NF2;       // also Ab (after qkv)
    unsigned short* Qb = (unsigned short*)w;  w += NF2;
    unsigned short* Kb = (unsigned short*)w;  w += NF2;
    unsigned short* Vb = (unsigned short*)w;  w += NF2;
    unsigned short* Wb = (unsigned short*)w;  w += (size_t)4 * 16384 * 2;
    float* wraw        = (float*)w;           w += (size_t)E * NHEAD * 4;
    float* segsum      = (float*)w;           w += (size_t)N * NHEAD * 4;  // zeroed
    int* counts        = (int*)w;             w += (size_t)N * 4;          // zeroed (contig w/ segsum)
    int* offsets       = (int*)w;             w += (size_t)N * 4;
    int* cursor        = (int*)w;             w += (size_t)N * 4;
    int* blocksums     = (int*)w;             w += 256 * 4;
    int* blockoffs     = (int*)w;             w += 256 * 4;
    int* rec           = (int*)w;             w += (size_t)E * 4;

    unsigned short* Ab = Xb;   // Xb dead after qkv

    // zero segsum + counts (contiguous)
    hipMemsetAsync(segsum, 0, ((size_t)N * NHEAD + N) * sizeof(float), stream);

    int e_blocks = (E + 255) / 256;          // 2344
    int x8 = N * FEAT / 8;
    int convx_blocks = (x8 + 255) / 256;     // 3125
    int convw_blocks = 32;
    prep_kernel<<<e_blocks + convx_blocks + convw_blocks, 256, 0, stream>>>(
        dsts, counts, X, Xb, x8, Wq, Wk, Wv, Wo, Wb,
        E, e_blocks, convx_blocks);

    int NB = (N + 255) / 256;   // 196
    scan1_kernel<<<NB, 256, 0, stream>>>(counts, offsets, blocksums, N);
    scan2_kernel<<<1, 256, 0, stream>>>(blocksums, blockoffs, NB);
    scan3_kernel<<<NB, 256, 0, stream>>>(offsets, blockoffs, cursor, N);

    fill_kernel<<<e_blocks, 256, 0, stream>>>(srcs, dsts, cursor, rec, E);

    int numTiles = NPAD / 16;   // 3128
    qkv_mfma_kernel<<<782, 256, 0, stream>>>(Xb, Wb, bq, bk, bv, Qb, Kb, Vb, N, numTiles);

    int node_blocks = (N + 3) / 4;
    sumexp_kernel<<<node_blocks, 256, 0, stream>>>(
        offsets, counts, rec, Qb, Kb, wraw, segsum, N);

    recip_kernel<<<(N * NHEAD + 255) / 256, 256, 0, stream>>>(segsum, N * NHEAD);

    gather_kernel<<<node_blocks, 256, 0, stream>>>(
        offsets, counts, rec, wraw, segsum, Vb, Ab, N);

    out_mfma_kernel<<<782, 256, 0, stream>>>(Ab, Wb + 3 * 16384, bo, out, N, numTiles);
}

// Round 9
// 276.311 us; speedup vs baseline: 1.4324x; 1.1030x over previous
//
#include <hip/hip_runtime.h>
#include <hip/hip_bf16.h>

// GAT-style graph attention. N=50000, E=600000, FEAT=128, H=8, D=16.
// R9: R8 minus fp8 V (fp8 quant pushed absmax to 0.091 > 0.07 — V errors
//     don't average away through the convex combination + Wo GEMM).
//     Keeps: shfl-free sumexp (lane=(edge-octet,head), K-slice in regs,
//     in-lane 16-dot, coalesced Q loads, exp once), bf16 wraw.

#define FEAT 128
#define NHEAD 8
#define NPAD 50048   // N rounded up to multiple of 64

typedef __attribute__((ext_vector_type(8))) short bf16x8;
typedef __attribute__((ext_vector_type(4))) float f32x4;

__device__ __forceinline__ unsigned short f2bf(float f) {
    unsigned u = __float_as_uint(f);
    u += 0x7fffu + ((u >> 16) & 1u);
    return (unsigned short)(u >> 16);
}
__device__ __forceinline__ float bf2f_lo(unsigned u) { return __uint_as_float(u << 16); }
__device__ __forceinline__ float bf2f_hi(unsigned u) { return __uint_as_float(u & 0xffff0000u); }
__device__ __forceinline__ float bfw(unsigned short u) { return __uint_as_float((unsigned)u << 16); }

// ---- fused prep: dest histogram | convert_x | convert_w ----
__global__ __launch_bounds__(256) void prep_kernel(
    const int* __restrict__ dsts, int* __restrict__ counts,
    const float* __restrict__ X, unsigned short* __restrict__ Xb, int total8,
    const float* __restrict__ Wq, const float* __restrict__ Wk,
    const float* __restrict__ Wv, const float* __restrict__ Wo,
    unsigned short* __restrict__ Wb,
    int E, int histBlocks, int convxBlocks)
{
    int b = blockIdx.x;
    if (b < histBlocks) {
        int e = b * 256 + threadIdx.x;
        if (e < E) atomicAdd(counts + dsts[e], 1);
        return;
    }
    b -= histBlocks;
    if (b < convxBlocks) {
        int i = b * 256 + threadIdx.x;
        if (i >= total8) return;
        const float4* xp = (const float4*)X + (size_t)i * 2;
        float4 x0 = xp[0], x1 = xp[1];
        uint4 o;
        o.x = (unsigned)f2bf(x0.x) | ((unsigned)f2bf(x0.y) << 16);
        o.y = (unsigned)f2bf(x0.z) | ((unsigned)f2bf(x0.w) << 16);
        o.z = (unsigned)f2bf(x1.x) | ((unsigned)f2bf(x1.y) << 16);
        o.w = (unsigned)f2bf(x1.z) | ((unsigned)f2bf(x1.w) << 16);
        ((uint4*)Xb)[i] = o;
        return;
    }
    b -= convxBlocks;
    int i = b * 256 + threadIdx.x;
    if (i >= 4 * 2048) return;
    int mat = i >> 11, idx = i & 2047;
    const float* W = (mat == 0) ? Wq : (mat == 1) ? Wk : (mat == 2) ? Wv : Wo;
    const float4* xp = (const float4*)W + (size_t)idx * 2;
    float4 x0 = xp[0], x1 = xp[1];
    uint4 o;
    o.x = (unsigned)f2bf(x0.x) | ((unsigned)f2bf(x0.y) << 16);
    o.y = (unsigned)f2bf(x0.z) | ((unsigned)f2bf(x0.w) << 16);
    o.z = (unsigned)f2bf(x1.x) | ((unsigned)f2bf(x1.y) << 16);
    o.w = (unsigned)f2bf(x1.z) | ((unsigned)f2bf(x1.w) << 16);
    ((uint4*)(Wb + (size_t)mat * 16384))[idx] = o;
}

// ---- exclusive scan over N dest-counts ----
__global__ __launch_bounds__(256) void scan1_kernel(
    const int* __restrict__ counts, int* __restrict__ offsets,
    int* __restrict__ blocksums, int NT)
{
    __shared__ int buf[256];
    int t = threadIdx.x, i = blockIdx.x * 256 + t;
    int v = (i < NT) ? counts[i] : 0;
    buf[t] = v; __syncthreads();
    int x = v;
    #pragma unroll
    for (int off = 1; off < 256; off <<= 1) {
        int y = (t >= off) ? buf[t - off] : 0;
        __syncthreads();
        x += y; buf[t] = x;
        __syncthreads();
    }
    if (i < NT) offsets[i] = x - v;
    if (t == 255) blocksums[blockIdx.x] = x;
}

__global__ __launch_bounds__(256) void scan2_kernel(
    int* __restrict__ blocksums, int* __restrict__ blockoffs, int NB)
{
    __shared__ int buf[256];
    int t = threadIdx.x;
    int v = (t < NB) ? blocksums[t] : 0;
    buf[t] = v; __syncthreads();
    int x = v;
    #pragma unroll
    for (int off = 1; off < 256; off <<= 1) {
        int y = (t >= off) ? buf[t - off] : 0;
        __syncthreads();
        x += y; buf[t] = x;
        __syncthreads();
    }
    if (t < NB) blockoffs[t] = x - v;
}

__global__ __launch_bounds__(256) void scan3_kernel(
    int* __restrict__ offsets, const int* __restrict__ blockoffs,
    int* __restrict__ cursor, int NT)
{
    int i = blockIdx.x * 256 + threadIdx.x;
    if (i < NT) {
        int o = offsets[i] + blockoffs[blockIdx.x];
        offsets[i] = o;
        cursor[i] = o;
    }
}

// ---- fill dest-CSR: ONE scattered 4B stream ----
__global__ __launch_bounds__(256) void fill_kernel(
    const int* __restrict__ srcs, const int* __restrict__ dsts,
    int* __restrict__ cursor, int* __restrict__ rec, int E)
{
    int e = blockIdx.x * 256 + threadIdx.x;
    if (e < E) {
        int s = srcs[e], d = dsts[e];
        int pd = atomicAdd(cursor + d, 1);
        __builtin_nontemporal_store(s, rec + pd);
    }
}

// ---- QKV MFMA GEMM: wave owns 32-col strip, B frags persistent in regs ----
__global__ __launch_bounds__(256) void qkv_mfma_kernel(
    const unsigned short* __restrict__ Xb, const unsigned short* __restrict__ Wb,
    const float* __restrict__ bq, const float* __restrict__ bk, const float* __restrict__ bv,
    unsigned short* __restrict__ Q, unsigned short* __restrict__ K,
    unsigned short* __restrict__ V, int N, int numTiles)
{
    const int lane = threadIdx.x & 63;
    const int wave = threadIdx.x >> 6;
    const int m = lane & 15, quad = lane >> 4;
    const int colbase = wave * 32;

    bf16x8 bfr[3][2][4];
    #pragma unroll
    for (int mat = 0; mat < 3; mat++)
        #pragma unroll
        for (int ctl = 0; ctl < 2; ctl++) {
            const unsigned short* wrow =
                Wb + mat * 16384 + (size_t)(colbase + ctl * 16 + m) * FEAT + quad * 8;
            #pragma unroll
            for (int kc = 0; kc < 4; kc++)
                bfr[mat][ctl][kc] = *(const bf16x8*)(wrow + kc * 32);
        }

    const float* bias_p[3] = {bq, bk, bv};
    float bias[3][2];
    #pragma unroll
    for (int mat = 0; mat < 3; mat++)
        #pragma unroll
        for (int ctl = 0; ctl < 2; ctl++)
            bias[mat][ctl] = bias_p[mat][colbase + ctl * 16 + m];

    unsigned short* outp[3] = {Q, K, V};

    for (int tile = blockIdx.x; tile < numTiles; tile += gridDim.x) {
        const int row0 = tile * 16;
        const unsigned short* arow = Xb + (size_t)(row0 + m) * FEAT + quad * 8;
        bf16x8 a[4];
        #pragma unroll
        for (int kc = 0; kc < 4; kc++) a[kc] = *(const bf16x8*)(arow + kc * 32);
        f32x4 acc[3][2];
        #pragma unroll
        for (int mat = 0; mat < 3; mat++)
            #pragma unroll
            for (int ctl = 0; ctl < 2; ctl++) acc[mat][ctl] = (f32x4){0.f, 0.f, 0.f, 0.f};
        #pragma unroll
        for (int kc = 0; kc < 4; kc++)
            #pragma unroll
            for (int mat = 0; mat < 3; mat++)
                #pragma unroll
                for (int ctl = 0; ctl < 2; ctl++)
                    acc[mat][ctl] = __builtin_amdgcn_mfma_f32_16x16x32_bf16(
                        a[kc], bfr[mat][ctl][kc], acc[mat][ctl], 0, 0, 0);
        #pragma unroll
        for (int mat = 0; mat < 3; mat++)
            #pragma unroll
            for (int ctl = 0; ctl < 2; ctl++)
                #pragma unroll
                for (int reg = 0; reg < 4; reg++) {
                    int row = row0 + quad * 4 + reg;
                    if (row < N)
                        outp[mat][(size_t)row * FEAT + colbase + ctl * 16 + m] =
                            f2bf(acc[mat][ctl][reg] + bias[mat][ctl]);
                }
    }
}

// ---- sumexp: one wave per DEST node, shfl-free.
//      lane = (edge-octet j=lane>>3, head h=lane&7). K slice (16 f32) in
//      regs; per 8-edge chunk: two coalesced dwordx4 Q-slice loads, full
//      in-lane dot, exp once, contiguous bf16 wraw store, atomicAdd
//      segsum[src*8+h] (L2-resident). ----
__global__ __launch_bounds__(256) void sumexp_kernel(
    const int* __restrict__ offsets, const int* __restrict__ counts,
    const int* __restrict__ rec,
    const unsigned short* __restrict__ Q, const unsigned short* __restrict__ K,
    unsigned short* __restrict__ wrawb, float* __restrict__ segsum, int N)
{
    int node = blockIdx.x * 4 + (threadIdx.x >> 6);
    if (node >= N) return;
    int lane = threadIdx.x & 63;
    int j = lane >> 3, h = lane & 7;
    int start = offsets[node], deg = counts[node];
    if (deg == 0) return;

    float kf[16];
    {
        const unsigned* kp = (const unsigned*)(K + (size_t)node * FEAT + h * 16);
        #pragma unroll
        for (int i = 0; i < 8; i++) {
            unsigned u = kp[i];
            kf[2 * i]     = bf2f_lo(u);
            kf[2 * i + 1] = bf2f_hi(u);
        }
    }

    for (int j0 = 0; j0 < deg; j0 += 8) {
        int jj = j0 + j;
        bool act = jj < deg;
        int pos = start + (act ? jj : j0);
        int s = rec[pos];
        const unsigned* qp = (const unsigned*)(Q + (size_t)s * FEAT + h * 16);
        uint4 qa = *(const uint4*)qp;
        uint4 qb = *(const uint4*)(qp + 4);
        float p;
        p  = bf2f_lo(qa.x) * kf[0]  + bf2f_hi(qa.x) * kf[1];
        p += bf2f_lo(qa.y) * kf[2]  + bf2f_hi(qa.y) * kf[3];
        p += bf2f_lo(qa.z) * kf[4]  + bf2f_hi(qa.z) * kf[5];
        p += bf2f_lo(qa.w) * kf[6]  + bf2f_hi(qa.w) * kf[7];
        p += bf2f_lo(qb.x) * kf[8]  + bf2f_hi(qb.x) * kf[9];
        p += bf2f_lo(qb.y) * kf[10] + bf2f_hi(qb.y) * kf[11];
        p += bf2f_lo(qb.z) * kf[12] + bf2f_hi(qb.z) * kf[13];
        p += bf2f_lo(qb.w) * kf[14] + bf2f_hi(qb.w) * kf[15];
        float w = __expf(p * 0.25f);
        if (act) {
            wrawb[(size_t)(start + j0) * NHEAD + lane] = f2bf(w);
            atomicAdd(segsum + (size_t)s * NHEAD + h, w);
        }
    }
}

// ---- reciprocal of segsum ----
__global__ __launch_bounds__(256) void recip_kernel(float* __restrict__ segsum, int n)
{
    int i = blockIdx.x * 256 + threadIdx.x;
    if (i < n) segsum[i] = 1.0f / segsum[i];
}

// ---- gather: one wave per dest node; bf16 V rows, bf16 wraw,
//      rsegsum[src] normalization, 4x-unrolled random V-row loads ----
__global__ __launch_bounds__(256) void gather_kernel(
    const int* __restrict__ offsets, const int* __restrict__ counts,
    const int* __restrict__ rec, const unsigned short* __restrict__ wrawb,
    const float* __restrict__ rsegsum, const unsigned short* __restrict__ V,
    unsigned short* __restrict__ agg, int N)
{
    int node = blockIdx.x * 4 + (threadIdx.x >> 6);
    if (node >= N) return;
    int lane = threadIdx.x & 63;
    int h = lane >> 3;
    int start = offsets[node], deg = counts[node];
    float ax = 0.f, ay = 0.f;
    int j = 0;
    for (; j + 4 <= deg; j += 4) {
        int p = start + j;
        int s0 = rec[p], s1 = rec[p + 1];
        int s2 = rec[p + 2], s3 = rec[p + 3];
        float w0 = bfw(wrawb[(size_t)(p + 0) * NHEAD + h]) * rsegsum[(size_t)s0 * NHEAD + h];
        float w1 = bfw(wrawb[(size_t)(p + 1) * NHEAD + h]) * rsegsum[(size_t)s1 * NHEAD + h];
        float w2 = bfw(wrawb[(size_t)(p + 2) * NHEAD + h]) * rsegsum[(size_t)s2 * NHEAD + h];
        float w3 = bfw(wrawb[(size_t)(p + 3) * NHEAD + h]) * rsegsum[(size_t)s3 * NHEAD + h];
        unsigned v0 = *(const unsigned*)(V + (size_t)s0 * FEAT + lane * 2);
        unsigned v1 = *(const unsigned*)(V + (size_t)s1 * FEAT + lane * 2);
        unsigned v2 = *(const unsigned*)(V + (size_t)s2 * FEAT + lane * 2);
        unsigned v3 = *(const unsigned*)(V + (size_t)s3 * FEAT + lane * 2);
        ax += w0 * bf2f_lo(v0) + w1 * bf2f_lo(v1) + w2 * bf2f_lo(v2) + w3 * bf2f_lo(v3);
        ay += w0 * bf2f_hi(v0) + w1 * bf2f_hi(v1) + w2 * bf2f_hi(v2) + w3 * bf2f_hi(v3);
    }
    for (; j < deg; j++) {
        int p = start + j;
        int s = rec[p];
        float w = bfw(wrawb[(size_t)p * NHEAD + h]) * rsegsum[(size_t)s * NHEAD + h];
        unsigned v = *(const unsigned*)(V + (size_t)s * FEAT + lane * 2);
        ax += w * bf2f_lo(v);
        ay += w * bf2f_hi(v);
    }
    unsigned o = (unsigned)f2bf(ax) | ((unsigned)f2bf(ay) << 16);
    *(unsigned*)(agg + (size_t)node * FEAT + lane * 2) = o;
}

// ---- out MFMA GEMM: persistent-B structure, 1 matrix, f32 out ----
__global__ __launch_bounds__(256) void out_mfma_kernel(
    const unsigned short* __restrict__ Ab, const unsigned short* __restrict__ Wob,
    const float* __restrict__ bo, float* __restrict__ out, int N, int numTiles)
{
    const int lane = threadIdx.x & 63;
    const int wave = threadIdx.x >> 6;
    const int m = lane & 15, quad = lane >> 4;
    const int colbase = wave * 32;

    bf16x8 bfr[2][4];
    #pragma unroll
    for (int ctl = 0; ctl < 2; ctl++) {
        const unsigned short* wrow = Wob + (size_t)(colbase + ctl * 16 + m) * FEAT + quad * 8;
        #pragma unroll
        for (int kc = 0; kc < 4; kc++)
            bfr[ctl][kc] = *(const bf16x8*)(wrow + kc * 32);
    }
    float bias[2];
    #pragma unroll
    for (int ctl = 0; ctl < 2; ctl++) bias[ctl] = bo[colbase + ctl * 16 + m];

    for (int tile = blockIdx.x; tile < numTiles; tile += gridDim.x) {
        const int row0 = tile * 16;
        const unsigned short* arow = Ab + (size_t)(row0 + m) * FEAT + quad * 8;
        bf16x8 a[4];
        #pragma unroll
        for (int kc = 0; kc < 4; kc++) a[kc] = *(const bf16x8*)(arow + kc * 32);
        f32x4 acc[2];
        #pragma unroll
        for (int ctl = 0; ctl < 2; ctl++) acc[ctl] = (f32x4){0.f, 0.f, 0.f, 0.f};
        #pragma unroll
        for (int kc = 0; kc < 4; kc++)
            #pragma unroll
            for (int ctl = 0; ctl < 2; ctl++)
                acc[ctl] = __builtin_amdgcn_mfma_f32_16x16x32_bf16(
                    a[kc], bfr[ctl][kc], acc[ctl], 0, 0, 0);
        #pragma unroll
        for (int ctl = 0; ctl < 2; ctl++)
            #pragma unroll
            for (int reg = 0; reg < 4; reg++) {
                int row = row0 + quad * 4 + reg;
                if (row < N)
                    out[(size_t)row * FEAT + colbase + ctl * 16 + m] = acc[ctl][reg] + bias[ctl];
            }
    }
}

extern "C" void kernel_launch(void* const* d_in, const int* in_sizes, int n_in,
                              void* d_out, int out_size, void* d_ws, size_t ws_size,
                              hipStream_t stream) {
    const float* X  = (const float*)d_in[0];
    const int*   ei = (const int*)d_in[1];
    const float* Wq = (const float*)d_in[2];
    const float* bq = (const float*)d_in[3];
    const float* Wk = (const float*)d_in[4];
    const float* bk = (const float*)d_in[5];
    const float* Wv = (const float*)d_in[6];
    const float* bv = (const float*)d_in[7];
    const float* Wo = (const float*)d_in[8];
    const float* bo = (const float*)d_in[9];
    float* out = (float*)d_out;

    const int N = in_sizes[0] / FEAT;        // 50000
    const int E = in_sizes[1] / 2;           // 600000
    const int* srcs = ei;
    const int* dsts = ei + E;
    const size_t NF2 = (size_t)NPAD * FEAT * 2;

    char* w = (char*)d_ws;
    unsigned short* Xb = (unsigned short*)w;  w += NF2;       // also Ab (after qkv)
    unsigned short* Qb = (unsigned short*)w;  w += NF2;
    unsigned short* Kb = (unsigned short*)w;  w += NF2;
    unsigned short* Vb = (unsigned short*)w;  w += NF2;
    unsigned short* Wb = (unsigned short*)w;  w += (size_t)4 * 16384 * 2;
    unsigned short* wrawb = (unsigned short*)w; w += (size_t)E * NHEAD * 2;  // bf16
    float* segsum      = (float*)w;           w += (size_t)N * NHEAD * 4;  // zeroed
    int* counts        = (int*)w;             w += (size_t)N * 4;          // zeroed (contig)
    int* offsets       = (int*)w;             w += (size_t)N * 4;
    int* cursor        = (int*)w;             w += (size_t)N * 4;
    int* blocksums     = (int*)w;             w += 256 * 4;
    int* blockoffs     = (int*)w;             w += 256 * 4;
    int* rec           = (int*)w;             w += (size_t)E * 4;

    unsigned short* Ab = Xb;   // Xb dead after qkv

    // zero segsum + counts (contiguous)
    hipMemsetAsync(segsum, 0, ((size_t)N * NHEAD + N) * sizeof(float), stream);

    int e_blocks = (E + 255) / 256;          // 2344
    int x8 = N * FEAT / 8;
    int convx_blocks = (x8 + 255) / 256;     // 3125
    int convw_blocks = 32;
    prep_kernel<<<e_blocks + convx_blocks + convw_blocks, 256, 0, stream>>>(
        dsts, counts, X, Xb, x8, Wq, Wk, Wv, Wo, Wb,
        E, e_blocks, convx_blocks);

    int NB = (N + 255) / 256;   // 196
    scan1_kernel<<<NB, 256, 0, stream>>>(counts, offsets, blocksums, N);
    scan2_kernel<<<1, 256, 0, stream>>>(blocksums, blockoffs, NB);
    scan3_kernel<<<NB, 256, 0, stream>>>(offsets, blockoffs, cursor, N);

    fill_kernel<<<e_blocks, 256, 0, stream>>>(srcs, dsts, cursor, rec, E);

    int numTiles = NPAD / 16;   // 3128
    qkv_mfma_kernel<<<782, 256, 0, stream>>>(Xb, Wb, bq, bk, bv, Qb, Kb, Vb, N, numTiles);

    int node_blocks = (N + 3) / 4;
    sumexp_kernel<<<node_blocks, 256, 0, stream>>>(
        offsets, counts, rec, Qb, Kb, wrawb, segsum, N);

    recip_kernel<<<(N * NHEAD + 255) / 256, 256, 0, stream>>>(segsum, N * NHEAD);

    gather_kernel<<<node_blocks, 256, 0, stream>>>(
        offsets, counts, rec, wrawb, segsum, Vb, Ab, N);

    out_mfma_kernel<<<782, 256, 0, stream>>>(Ab, Wb + 3 * 16384, bo, out, N, numTiles);
}